// Round 3
// baseline (22.022 us; speedup 1.0000x reference)
//
#include <hip/hip_runtime.h>

// Product_50242527428657: out[b,o] = prod_k (x[b,k]*w[o,k] + 1) - 1 + bias[o]   (ALPHA==1)
// B=1024, IN=256, OUT=512, fp32. No fp32 MFMA -> pure VALU kernel; floor ~3.4us.
//
// Round-3: round-2 spilled (34.8MB scratch writes, 265B/thread: unrolled p-loop kept
// 4 generations of xv[8]+wv[8] live over acc[8][8]). Fixes:
//  - p-loop NOT unrolled (#pragma unroll 1): live set = acc 64 + wv 32 + xv 4 + addr ~ 110 VGPR.
//  - combine-store swizzle (cg ^ (row&7) ^ 2*(row>>3)): round-2's 459K bank conflicts were
//    the 16-way-conflicted scalar combine stores; swizzle makes them 2-way (free).
// Structure: 512 blocks (32x32 out tile), 256 thr, 2 blocks/CU (LDS 66.5KB), 8x8 reg tile,
// 16-way K-split, shfl_xor in-wave combine + 16KB LDS cross-wave combine.

#define BATCH 1024
#define IN    256
#define OUT   512
#define NK4   (IN / 4)     // 64 float4 chunks along K
#define LDK   (NK4 + 1)    // 65: +1 chunk row pad -> conflict-free with linear addressing

__device__ __forceinline__ int swz(int row) {            // combine-store swizzle
    return (row & 7) ^ ((2 * (row >> 3)) & 7);
}

__global__ __launch_bounds__(256, 2) void product_kernel(
    const float* __restrict__ x, const float* __restrict__ w,
    const float* __restrict__ bias, float* __restrict__ out)
{
    __shared__ float4 xs4[32 * LDK];   // 33.28 KB
    __shared__ float4 ws4[32 * LDK];   // 33.28 KB

    const int tid  = threadIdx.x;
    const int tx   = tid & 3;          // w-row group: cols tx + 4j
    const int ty   = (tid >> 2) & 3;   // x-row group: rows ty + 4i
    const int sbl  = (tid >> 4) & 3;   // k-split index within wave
    const int wid  = tid >> 6;         // wave 0..3
    const int sb   = wid * 4 + sbl;    // k-split 0..15: k in [sb*16, sb*16+16)
    const int lane = tid & 63;

    const int o0 = blockIdx.x * 32;
    const int b0 = blockIdx.y * 32;

    const float4* x4g = (const float4*)x;   // [1024][64]
    const float4* w4g = (const float4*)w;   // [512][64]

    // ---- stage full-K tiles (coalesced 1KB/wave rows; stride-16B LDS writes = conflict-free)
    #pragma unroll
    for (int it = 0; it < 16; ++it) {
        const int idx = it * 4 + wid;
        if (idx < 32) xs4[idx * LDK + lane]        = x4g[(b0 + idx) * NK4 + lane];
        else          ws4[(idx - 32) * LDK + lane] = w4g[(o0 + idx - 32) * NK4 + lane];
    }
    __syncthreads();

    // ---- main loop: 4 chunks (16 k) per thread, 8x8 accumulators ----
    float acc[8][8];
    #pragma unroll
    for (int i = 0; i < 8; ++i)
        #pragma unroll
        for (int j = 0; j < 8; ++j) acc[i][j] = 1.0f;

    const float4* xb = xs4 + ty * LDK + sb * 4;
    const float4* wb = ws4 + tx * LDK + sb * 4;

    #pragma unroll 1                       // keep exactly one chunk-generation live
    for (int p = 0; p < 4; ++p) {
        float4 wv[8];
        #pragma unroll
        for (int j = 0; j < 8; ++j) wv[j] = wb[j * 4 * LDK + p];

        #pragma unroll
        for (int i = 0; i < 8; ++i) {
            const float4 xv = xb[i * 4 * LDK + p];
            #define KSTEP(COMP)                                              \
            {   const float xc = xv.COMP;                                    \
                _Pragma("unroll")                                            \
                for (int j = 0; j < 8; ++j)                                  \
                    acc[i][j] *= __builtin_fmaf(xc, wv[j].COMP, 1.0f);       \
            }
            KSTEP(x) KSTEP(y) KSTEP(z) KSTEP(w)
            #undef KSTEP
        }
    }

    // ---- combine 1: multiply partials across sbl (lane bits 4,5) in-wave ----
    #pragma unroll
    for (int i = 0; i < 8; ++i)
        #pragma unroll
        for (int j = 0; j < 8; ++j) {
            float v = acc[i][j];
            v *= __shfl_xor(v, 16, 64);
            v *= __shfl_xor(v, 32, 64);
            acc[i][j] = v;
        }

    // ---- combine 2: cross-wave via LDS (alias xs4; barrier-protected, swizzled stores) ----
    __syncthreads();
    float* part = (float*)xs4;             // [4 waves][32 rows][8 cg][4] = 16 KB
    #pragma unroll
    for (int ii = 0; ii < 2; ++ii) {       // lane sbl stores rows i = 2*sbl + ii
        const int i   = sbl * 2 + ii;
        const int row = ty + 4 * i;
        const int sw  = swz(row);
        #pragma unroll
        for (int j = 0; j < 8; ++j)
            part[wid * 1024 + row * 32 + ((j ^ sw) << 2) + tx] = acc[i][j];
    }
    __syncthreads();

    // ---- epilogue: multiply 4 wave-partials, -1 + bias, coalesced float4 store ----
    const int row = tid >> 3;              // 0..31
    const int cg  = tid & 7;               // logical float4 col group
    const int pcg = cg ^ swz(row);         // physical (swizzled) col group
    const float4* part4 = (const float4*)part;
    const float4 q0 = part4[0 * 256 + row * 8 + pcg];
    const float4 q1 = part4[1 * 256 + row * 8 + pcg];
    const float4 q2 = part4[2 * 256 + row * 8 + pcg];
    const float4 q3 = part4[3 * 256 + row * 8 + pcg];
    const float4 bv = ((const float4*)bias)[(o0 >> 2) + cg];
    float4 o;
    o.x = ((q0.x * q1.x) * q2.x) * q3.x - 1.0f + bv.x;
    o.y = ((q0.y * q1.y) * q2.y) * q3.y - 1.0f + bv.y;
    o.z = ((q0.z * q1.z) * q2.z) * q3.z - 1.0f + bv.z;
    o.w = ((q0.w * q1.w) * q2.w) * q3.w - 1.0f + bv.w;
    ((float4*)out)[(size_t)(b0 + row) * (OUT / 4) + (o0 >> 2) + cg] = o;
}

extern "C" void kernel_launch(void* const* d_in, const int* in_sizes, int n_in,
                              void* d_out, int out_size, void* d_ws, size_t ws_size,
                              hipStream_t stream) {
    const float* x    = (const float*)d_in[0];   // (1024, 256)
    const float* wgt  = (const float*)d_in[1];   // (512, 256)
    const float* bias = (const float*)d_in[2];   // (512,)
    float* out        = (float*)d_out;           // (1024, 512)

    dim3 grid(OUT / 32, BATCH / 32);   // (16, 32) = 512 blocks
    dim3 block(256);
    product_kernel<<<grid, block, 0, stream>>>(x, wgt, bias, out);
}

// Round 4
// 15.312 us; speedup vs baseline: 1.4382x; 1.4382x over previous
//
#include <hip/hip_runtime.h>

// Product_50242527428657: out[b,o] = prod_k (x[b,k]*w[o,k] + 1) - 1 + bias[o]   (ALPHA==1)
// B=1024, IN=256, OUT=512, fp32. Pure VALU kernel (no fp32 MFMA); VALU floor 3.4us.
//
// Round-4: eliminate the shuffle combine (R3: 128 ds_bpermute/thread ~ 3.4us/CU on the
// LDS pipe) and keep the live set small enough that spilling is impossible.
//  - 512 blocks (8 o-tiles x 64 b-tiles), 256 thr, 2 blocks/CU (LDS 80KB exactly).
//  - Per-thread: ALL 16 block rows x 4 cols (float4 acc[16]), k-split 16 (wid,sbl).
//    x reads are 4-address multicast b128; w reads per-lane b128.
//  - Bank math: ws phys chunk = c ^ ((row>>2)&7): row>>2 == l4 for lane's 4 rows ->
//    64 lanes spread evenly over all 8 bank groups (naive layout was parity-locked
//    -> 16-way). xs phys chunk = c ^ (row&7): multicast reads, 2-way max (free).
//  - Combine via LDS only: 16 b128 stores/thread into part[16s][16r][16c4] (aliases
//    ws4, barrier-protected), epilogue multiplies 16 partials in fixed s order.
//  - Live set: acc 64 + wv 16 + xv 4 + addr ~= 95 VGPR. p-loop unroll 1.

#define BATCH 1024
#define IN    256
#define OUT   512

__global__ __launch_bounds__(256, 2) void product_kernel(
    const float* __restrict__ x, const float* __restrict__ w,
    const float* __restrict__ bias, float* __restrict__ out)
{
    __shared__ float4 xs4[16 * 64];   // 16 KB: x rows b0..b0+15, 64 chunks, swz c^(row&7)
    __shared__ float4 ws4[64 * 64];   // 64 KB: w rows o0..o0+63, swz c^((row>>2)&7)

    const int tid  = threadIdx.x;
    const int wid  = tid >> 6;        // wave 0..3
    const int lane = tid & 63;
    const int sbl  = lane >> 4;       // in-wave k-split 0..3
    const int l4   = lane & 15;       // col group: cols o0 + 4*l4 .. +3
    const int s    = wid * 4 + sbl;   // k-split 0..15: chunks [4s, 4s+4)

    const int o0 = blockIdx.x * 64;
    const int b0 = blockIdx.y * 16;

    const float4* x4g = (const float4*)x;   // [1024][64]
    const float4* w4g = (const float4*)w;   // [512][64]

    // ---- stage: 80 rows of 64 chunks; wave writes whole rows (lane==chunk ->
    //      phys = lane ^ const = permutation, conflict-free; global coalesced) ----
    #pragma unroll
    for (int it = 0; it < 20; ++it) {
        const int idx = it * 4 + wid;                       // 0..79
        if (idx < 16) {
            xs4[idx * 64 + (lane ^ (idx & 7))] = x4g[(b0 + idx) * 64 + lane];
        } else {
            const int r = idx - 16;                         // 0..63
            ws4[r * 64 + (lane ^ ((r >> 2) & 7))] = w4g[(o0 + r) * 64 + lane];
        }
    }
    __syncthreads();

    // ---- main: 4 chunks (16 k) per thread over 16 rows x 4 cols ----
    float4 acc[16];
    #pragma unroll
    for (int i = 0; i < 16; ++i) acc[i] = make_float4(1.0f, 1.0f, 1.0f, 1.0f);

    const int wsw = l4 & 7;           // ws swizzle for rows 4*l4+j (row>>2 == l4)
    const int wr  = 4 * l4 * 64;      // base of lane's w rows

    #pragma unroll 1                  // one chunk-generation live at a time
    for (int p = 0; p < 4; ++p) {
        const int c  = 4 * s + p;     // logical chunk
        const int cw = c ^ wsw;
        const float4 wv0 = ws4[wr + 0 * 64 + cw];
        const float4 wv1 = ws4[wr + 1 * 64 + cw];
        const float4 wv2 = ws4[wr + 2 * 64 + cw];
        const float4 wv3 = ws4[wr + 3 * 64 + cw];
        #pragma unroll
        for (int i = 0; i < 16; ++i) {
            const float4 xv = xs4[i * 64 + (c ^ (i & 7))];
            acc[i].x *= __builtin_fmaf(xv.x, wv0.x, 1.0f);
            acc[i].y *= __builtin_fmaf(xv.x, wv1.x, 1.0f);
            acc[i].z *= __builtin_fmaf(xv.x, wv2.x, 1.0f);
            acc[i].w *= __builtin_fmaf(xv.x, wv3.x, 1.0f);
            acc[i].x *= __builtin_fmaf(xv.y, wv0.y, 1.0f);
            acc[i].y *= __builtin_fmaf(xv.y, wv1.y, 1.0f);
            acc[i].z *= __builtin_fmaf(xv.y, wv2.y, 1.0f);
            acc[i].w *= __builtin_fmaf(xv.y, wv3.y, 1.0f);
            acc[i].x *= __builtin_fmaf(xv.z, wv0.z, 1.0f);
            acc[i].y *= __builtin_fmaf(xv.z, wv1.z, 1.0f);
            acc[i].z *= __builtin_fmaf(xv.z, wv2.z, 1.0f);
            acc[i].w *= __builtin_fmaf(xv.z, wv3.z, 1.0f);
            acc[i].x *= __builtin_fmaf(xv.w, wv0.w, 1.0f);
            acc[i].y *= __builtin_fmaf(xv.w, wv1.w, 1.0f);
            acc[i].z *= __builtin_fmaf(xv.w, wv2.w, 1.0f);
            acc[i].w *= __builtin_fmaf(xv.w, wv3.w, 1.0f);
        }
    }

    // ---- combine: partials -> LDS (aliases ws4; all ws reads done), fixed order ----
    __syncthreads();
    float4* part4 = (float4*)ws4;     // [16 s][16 r][16 c4] float4 = 64 KB exactly
    #pragma unroll
    for (int i = 0; i < 16; ++i)
        part4[(s * 16 + i) * 16 + l4] = acc[i];
    __syncthreads();

    // ---- epilogue: thread -> (row r, col-group c4); prod over s; -1 + bias ----
    const int r  = tid >> 4;          // 0..15
    const int c4 = tid & 15;          // 0..15
    float4 pr = part4[r * 16 + c4];   // s = 0
    #pragma unroll
    for (int ss = 1; ss < 16; ++ss) {
        const float4 q = part4[(ss * 16 + r) * 16 + c4];
        pr.x *= q.x; pr.y *= q.y; pr.z *= q.z; pr.w *= q.w;
    }
    const float4 bv = ((const float4*)bias)[(o0 >> 2) + c4];
    float4 o;
    o.x = pr.x - 1.0f + bv.x;
    o.y = pr.y - 1.0f + bv.y;
    o.z = pr.z - 1.0f + bv.z;
    o.w = pr.w - 1.0f + bv.w;
    ((float4*)out)[(size_t)(b0 + r) * (OUT / 4) + (o0 >> 2) + c4] = o;
}

extern "C" void kernel_launch(void* const* d_in, const int* in_sizes, int n_in,
                              void* d_out, int out_size, void* d_ws, size_t ws_size,
                              hipStream_t stream) {
    const float* x    = (const float*)d_in[0];   // (1024, 256)
    const float* wgt  = (const float*)d_in[1];   // (512, 256)
    const float* bias = (const float*)d_in[2];   // (512,)
    float* out        = (float*)d_out;           // (1024, 512)

    dim3 grid(OUT / 64, BATCH / 16);   // (8, 64) = 512 blocks
    dim3 block(256);
    product_kernel<<<grid, block, 0, stream>>>(x, wgt, bias, out);
}

// Round 5
// 14.041 us; speedup vs baseline: 1.5684x; 1.0905x over previous
//
#include <hip/hip_runtime.h>

// Product_50242527428657: out[b,o] = prod_k (x[b,k]*w[o,k] + 1) - 1 + bias[o]   (ALPHA==1)
// B=1024, IN=256, OUT=512, fp32. Pure VALU kernel (no fp32 MFMA); VALU floor 3.4us/CU.
//
// Round-5: R4's LDS pipe carried ~132 b128/thread (~5.3us/CU) vs 3.4us VALU. The 64 xv
// reads/thread have ZERO in-block reuse (each x-chunk read once per block) -> staging x
// through LDS wastes a write+read on the LDS pipe. Fix: read x chunks directly from
// global (L2-resident, VMEM pipe) into registers; keep only w (4x in-block reuse) in LDS.
//  - LDS/thread: 16 stage-w + 16 wv + 32 combine = 64 b128 ~= 2.6us/CU < VALU 3.4us.
//  - LDS = 64KB (w tile only) -> still 2 blocks/CU, 8 waves/CU.
//  - Geometry unchanged from R4: 512 blocks (8 o-tiles x 64 b-tiles), 256 thr,
//    per-thread 16 rows x 4 cols, 16-way k-split (wid,sbl), LDS-only combine.
//  - VGPR: acc 64 + xv 64 + wv 16 + addr ~165 < 256 cap (launch_bounds 256,2): no spill.

#define BATCH 1024
#define IN    256
#define OUT   512

__global__ __launch_bounds__(256, 2) void product_kernel(
    const float* __restrict__ x, const float* __restrict__ w,
    const float* __restrict__ bias, float* __restrict__ out)
{
    __shared__ float4 ws4[64 * 64];   // 64 KB: w rows o0..o0+63, phys chunk = c ^ ((row>>2)&7)

    const int tid  = threadIdx.x;
    const int wid  = tid >> 6;        // wave 0..3
    const int lane = tid & 63;
    const int sbl  = lane >> 4;       // in-wave k-split 0..3
    const int l4   = lane & 15;       // col group: cols o0 + 4*l4 .. +3
    const int s    = wid * 4 + sbl;   // k-split 0..15: chunks [4s, 4s+4)

    const int o0 = blockIdx.x * 64;
    const int b0 = blockIdx.y * 16;

    const float4* x4g = (const float4*)x;   // [1024][64]
    const float4* w4g = (const float4*)w;   // [512][64]

    // ---- stage w tile only: 64 rows x 64 chunks; wave writes whole rows
    //      (lane==chunk -> phys = lane ^ const = permutation, conflict-free) ----
    #pragma unroll
    for (int it = 0; it < 16; ++it) {
        const int r = it * 4 + wid;                         // 0..63, wave-uniform
        ws4[r * 64 + (lane ^ ((r >> 2) & 7))] = w4g[(o0 + r) * 64 + lane];
    }
    __syncthreads();

    // ---- main: 4 chunks (16 k) per thread over 16 rows x 4 cols ----
    float4 acc[16];
    #pragma unroll
    for (int i = 0; i < 16; ++i) acc[i] = make_float4(1.0f, 1.0f, 1.0f, 1.0f);

    const int wsw = l4 & 7;           // ws swizzle for rows 4*l4+j (row>>2 == l4)
    const int wr  = 4 * l4 * 64;      // base chunk of lane's 4 w rows

    #pragma unroll 1                  // one chunk-generation live at a time
    for (int p = 0; p < 4; ++p) {
        const int c = 4 * s + p;      // logical chunk (per-16-lane-group)

        // x chunks straight from global (L2-hot; 4 distinct 16B addrs per instr,
        // 16 independent loads in flight -> latency hidden under 512 VALU cyc)
        float4 xv[16];
        #pragma unroll
        for (int i = 0; i < 16; ++i) xv[i] = x4g[(b0 + i) * 64 + c];

        const int cw = c ^ wsw;
        const float4 wv0 = ws4[wr + 0 * 64 + cw];
        const float4 wv1 = ws4[wr + 1 * 64 + cw];
        const float4 wv2 = ws4[wr + 2 * 64 + cw];
        const float4 wv3 = ws4[wr + 3 * 64 + cw];

        #pragma unroll
        for (int i = 0; i < 16; ++i) {
            acc[i].x *= __builtin_fmaf(xv[i].x, wv0.x, 1.0f);
            acc[i].y *= __builtin_fmaf(xv[i].x, wv1.x, 1.0f);
            acc[i].z *= __builtin_fmaf(xv[i].x, wv2.x, 1.0f);
            acc[i].w *= __builtin_fmaf(xv[i].x, wv3.x, 1.0f);
            acc[i].x *= __builtin_fmaf(xv[i].y, wv0.y, 1.0f);
            acc[i].y *= __builtin_fmaf(xv[i].y, wv1.y, 1.0f);
            acc[i].z *= __builtin_fmaf(xv[i].y, wv2.y, 1.0f);
            acc[i].w *= __builtin_fmaf(xv[i].y, wv3.y, 1.0f);
            acc[i].x *= __builtin_fmaf(xv[i].z, wv0.z, 1.0f);
            acc[i].y *= __builtin_fmaf(xv[i].z, wv1.z, 1.0f);
            acc[i].z *= __builtin_fmaf(xv[i].z, wv2.z, 1.0f);
            acc[i].w *= __builtin_fmaf(xv[i].z, wv3.z, 1.0f);
            acc[i].x *= __builtin_fmaf(xv[i].w, wv0.w, 1.0f);
            acc[i].y *= __builtin_fmaf(xv[i].w, wv1.w, 1.0f);
            acc[i].z *= __builtin_fmaf(xv[i].w, wv2.w, 1.0f);
            acc[i].w *= __builtin_fmaf(xv[i].w, wv3.w, 1.0f);
        }
    }

    // ---- combine: partials -> LDS (aliases ws4; all wv reads done), fixed order ----
    __syncthreads();
    float4* part4 = (float4*)ws4;     // [16 s][16 r][16 c4] float4 = 64 KB exactly
    #pragma unroll
    for (int i = 0; i < 16; ++i)
        part4[(s * 16 + i) * 16 + l4] = acc[i];
    __syncthreads();

    // ---- epilogue: thread -> (row r, col-group c4); prod over s; -1 + bias ----
    const int r  = tid >> 4;          // 0..15
    const int c4 = tid & 15;          // 0..15
    float4 pr = part4[r * 16 + c4];   // s = 0
    #pragma unroll
    for (int ss = 1; ss < 16; ++ss) {
        const float4 q = part4[(ss * 16 + r) * 16 + c4];
        pr.x *= q.x; pr.y *= q.y; pr.z *= q.z; pr.w *= q.w;
    }
    const float4 bv = ((const float4*)bias)[(o0 >> 2) + c4];
    float4 o;
    o.x = pr.x - 1.0f + bv.x;
    o.y = pr.y - 1.0f + bv.y;
    o.z = pr.z - 1.0f + bv.z;
    o.w = pr.w - 1.0f + bv.w;
    ((float4*)out)[(size_t)(b0 + r) * (OUT / 4) + (o0 >> 2) + c4] = o;
}

extern "C" void kernel_launch(void* const* d_in, const int* in_sizes, int n_in,
                              void* d_out, int out_size, void* d_ws, size_t ws_size,
                              hipStream_t stream) {
    const float* x    = (const float*)d_in[0];   // (1024, 256)
    const float* wgt  = (const float*)d_in[1];   // (512, 256)
    const float* bias = (const float*)d_in[2];   // (512,)
    float* out        = (float*)d_out;           // (1024, 512)

    dim3 grid(OUT / 64, BATCH / 16);   // (8, 64) = 512 blocks
    dim3 block(256);
    product_kernel<<<grid, block, 0, stream>>>(x, wgt, bias, out);
}